// Round 1
// baseline (165.494 us; speedup 1.0000x reference)
//
#include <hip/hip_runtime.h>

#define BATCH   131072
#define NB      32          // N_BLOCKS
#define DIM     128         // 2*NB + M_REAL
#define DT      0.01f
#define VEC_PER_ROW (DIM / 4)   // 32 float4 per row

__global__ __launch_bounds__(256) void
koopman_kernel(const float4* __restrict__ x4,
               const float*  __restrict__ L,
               float4* __restrict__ out4)
{
    int t = blockIdx.x * blockDim.x + threadIdx.x;   // one float4 per thread
    // t in [0, BATCH * VEC_PER_ROW); grid sized exactly.
    int row = t >> 5;          // t / 32
    int j   = t & 31;          // float4 index within the row

    float4 xv = x4[t];
    const float* Lr = L + (size_t)row * DIM;
    float4 o;

    if (j < 16) {
        // complex pairs p0 = 2j, p1 = 2j+1
        float2 mu = *(const float2*)(Lr + 2 * j);        // cols 2j, 2j+1
        float2 om = *(const float2*)(Lr + NB + 2 * j);   // cols 32+2j, 32+2j+1

        float e0 = __expf(mu.x * DT);
        float e1 = __expf(mu.y * DT);
        float s0, c0, s1, c1;
        __sincosf(om.x * DT, &s0, &c0);
        __sincosf(om.y * DT, &s1, &c1);

        o.x = e0 * (c0 * xv.x - s0 * xv.y);
        o.y = e0 * (s0 * xv.x + c0 * xv.y);
        o.z = e1 * (c1 * xv.z - s1 * xv.w);
        o.w = e1 * (s1 * xv.z + c1 * xv.w);
    } else {
        // real part: output cols 4j..4j+3 (>= 64); lam lives at the SAME cols
        float4 lam = *(const float4*)(Lr + 4 * j);
        o.x = __expf(lam.x * DT) * xv.x;
        o.y = __expf(lam.y * DT) * xv.y;
        o.z = __expf(lam.z * DT) * xv.z;
        o.w = __expf(lam.w * DT) * xv.w;
    }

    out4[t] = o;
}

extern "C" void kernel_launch(void* const* d_in, const int* in_sizes, int n_in,
                              void* d_out, int out_size, void* d_ws, size_t ws_size,
                              hipStream_t stream)
{
    const float4* x4 = (const float4*)d_in[0];
    const float*  L  = (const float*)d_in[1];
    float4* out4     = (float4*)d_out;

    const int total_vec = BATCH * VEC_PER_ROW;       // 4,194,304
    const int block = 256;
    const int grid  = total_vec / block;             // 16384

    koopman_kernel<<<grid, block, 0, stream>>>(x4, L, out4);
}